// Round 11
// baseline (186.864 us; speedup 1.0000x reference)
//
#include <hip/hip_runtime.h>
#include <hip/hip_bf16.h>
#include <math.h>

// CrossGeometricStructureEmbedding, round 11.
// R10 post-mortem: fill duplication costs 23us of quarter-rate trans-pipe
// VALU (51 vs 28us single-fill); MFMA floor 28-30us invariant. Compiler
// re-loads B per phase from L2 regardless (VGPR=64 proved it) and that's
// FINE at phase granularity — the rule is "no ks-granular B loads", not
// "W must be resident". R11 = R10's occupancy (3 waves/SIMD, each wave
// from a DIFFERENT block -> max barrier stagger) + R7's single fill
// (256-thr block covers all 256 cols; wave owns 64 cols, acc[2][2]=64
// AGPR). B per phase in two 64-VGPR batches: batch1 issued before fill
// (lands during fill+barrier), batch2 between gemm halves (covered by
// the other 2 resident waves). Peak regs ~158 < (256,3) cap 170 => no
// spill. Phases interleave (q,d),(q,a); dmx carried in 2 regs. LDS
// ~35.5KB, grid 1024 (P=4): 3 resident blocks/CU.

typedef __attribute__((ext_vector_type(8))) short short8;
typedef __attribute__((ext_vector_type(16))) float f32x16;
typedef __attribute__((ext_vector_type(4))) unsigned int uint4v;

#define HH 256
#define P_PTS 4
#define NPTS 4096

__device__ __forceinline__ unsigned short f2bf(float f) {
    union { float f; unsigned int u; } v; v.f = f;
    unsigned int r = v.u + 0x7fffu + ((v.u >> 16) & 1u);  // RNE
    return (unsigned short)(r >> 16);
}

__device__ __forceinline__ unsigned int pack_sc(float s, float c) {
    union { __hip_bfloat162 h; unsigned int u; } v;
    v.h = __float22bfloat162_rn(make_float2(s, c));  // low = sin, high = cos
    return v.u;
}

__global__ __launch_bounds__(256)
void prep_w_kernel(const float* __restrict__ Wa, const float* __restrict__ Wd,
                   unsigned short* __restrict__ wbf) {
    int i = blockIdx.x * 256 + threadIdx.x;
    if (i < HH * HH) {
        wbf[i] = f2bf(Wd[i]);             // [0, 65536): Wd bf16
        wbf[HH * HH + i] = f2bf(Wa[i]);   // [65536, 131072): Wa bf16
    }
}

// E chunk addressing (validated xor swizzle): 16B chunks, 32 per row.
__device__ __forceinline__ int eoff(int r, int ch) {
    return r * HH + (((ch ^ (r & 7)) & 31) << 3);
}

__global__ __launch_bounds__(256, 3)
void cgse_main(const float* __restrict__ points,
               const float* __restrict__ anchors,
               const unsigned short* __restrict__ wbf,
               const float* __restrict__ ba,
               const float* __restrict__ bd,
               float* __restrict__ out) {
    __shared__ __align__(16) unsigned short E[64 * HH];   // 32 KB single buf
    __shared__ float xsd[P_PTS][64], xsa[P_PTS][64];      // 2 KB
    __shared__ float anch[192];

    const int tid = threadIdx.x;
    const int wave = tid >> 6, lane = tid & 63;
    const int l5 = lane & 31, half = lane >> 5;
    const int base = blockIdx.x * P_PTS;
    const int colw = wave * 64;                  // this wave's 64-col strip

    // ---- anchors + geometry: 4 points x 64 anchors = 256 tasks, 1/thread
    if (tid < 192) anch[tid] = anchors[tid];
    __syncthreads();
    {
        const int pt = wave, k = lane, k2 = (k + 1) & 63;  // roll(-1)
        const int pn = base + pt;
        const float px = points[pn * 3 + 0], py = points[pn * 3 + 1], pz = points[pn * 3 + 2];
        const float r1x = px - anch[k * 3 + 0];
        const float r1y = py - anch[k * 3 + 1];
        const float r1z = pz - anch[k * 3 + 2];
        const float r2x = px - anch[k2 * 3 + 0];
        const float r2y = py - anch[k2 * 3 + 1];
        const float r2z = pz - anch[k2 * 3 + 2];
        xsd[pt][k] = sqrtf(r1x * r1x + r1y * r1y + r1z * r1z) * 5.0f;  // /SIGMA_D
        const float cx = r1y * r2z - r1z * r2y;
        const float cy = r1z * r2x - r1x * r2z;
        const float cz = r1x * r2y - r1y * r2x;
        const float sv = sqrtf(cx * cx + cy * cy + cz * cz);
        const float cv = r1x * r2x + r1y * r2y + r1z * r2z;
        xsa[pt][k] = atan2f(sv, cv) * 3.8197186342054885f;  // *180/(15*pi)
    }

    float bias[2];
    #pragma unroll
    for (int nt = 0; nt < 2; ++nt)
        bias[nt] = ba[colw + nt * 32 + l5] + bd[colw + nt * 32 + l5];

    // fill constants: omega_i = x * rho^i / 2pi, rho = 1e4^(-1/128).
    // wave fills chunk cols [8w, 8w+8): i = 32w + 4c + j.
    const float cw = 0.15915494309189535f * __expf(-(float)wave * 2.302585092994046f);
    const float DC[8] = {1.0f, 0.7498942093324559f, 0.5623413251903491f,
                         0.4216965034285822f, 0.31622776601683794f,
                         0.23713737056616552f, 0.1778279410038923f,
                         0.13335214321633242f};

    // B base for this lane (nt=0 tile); nt=1 at +32*HH, type at +HH*HH.
    const unsigned short* wb0 = wbf + (colw + l5) * HH + half * 8;

    float dmx[2] = {0.f, 0.f};
    __syncthreads();  // xs ready

    // 8 phases: ph = 2q + type (type 0 = d/Wd, 1 = a/Wa)
    #pragma unroll 1
    for (int ph = 0; ph < 2 * P_PTS; ++ph) {
        const int q = ph >> 1, type = ph & 1;
        const unsigned short* wb = wb0 + type * (HH * HH);

        __syncthreads();  // all waves done reading E from previous phase

        // batch1: B for ks 0..7, both nt (64 VGPRs); lands during fill+barrier
        short8 bw[2][8];
        #pragma unroll
        for (int ks = 0; ks < 8; ++ks) {
            bw[0][ks] = *(const short8*)(wb + ks * 16);
            bw[1][ks] = *(const short8*)(wb + 32 * HH + ks * 16);
        }

        // ---- fill E (whole 64x256 tile; 8 chunks per thread, row = lane)
        {
            const float xr = (type ? xsa[q][lane] : xsd[q][lane]) * cw;
            #pragma unroll
            for (int c = 0; c < 8; ++c) {
                const float t0 = xr * DC[c];
                const float tt[4] = {t0, t0 * 0.9305720409297085f,
                                     t0 * 0.8659643233600653f,
                                     t0 * 0.8058421877614819f};
                uint4v w;
                #pragma unroll
                for (int j = 0; j < 4; ++j) {
                    const float f = tt[j] - floorf(tt[j]);  // revolutions
                    w[j] = pack_sc(__builtin_amdgcn_sinf(f),
                                   __builtin_amdgcn_cosf(f));
                }
                *(uint4v*)&E[eoff(lane, 8 * wave + c)] = w;
            }
        }
        __syncthreads();  // E ready (batch1 drained here too — already landed)

        f32x16 acc[2][2];
        #pragma unroll
        for (int mt = 0; mt < 2; ++mt)
            #pragma unroll
            for (int nt = 0; nt < 2; ++nt)
                #pragma unroll
                for (int r = 0; r < 16; ++r) acc[mt][nt][r] = 0.f;

        // gemm half 1: ks 0..7
        #pragma unroll
        for (int ks = 0; ks < 8; ++ks) {
            #pragma unroll
            for (int mt = 0; mt < 2; ++mt) {
                const short8 afr = *(const short8*)
                    &E[eoff(mt * 32 + l5, 2 * ks + half)];
                acc[mt][0] = __builtin_amdgcn_mfma_f32_32x32x16_bf16(
                    afr, bw[0][ks], acc[mt][0], 0, 0, 0);
                acc[mt][1] = __builtin_amdgcn_mfma_f32_32x32x16_bf16(
                    afr, bw[1][ks], acc[mt][1], 0, 0, 0);
            }
        }

        // batch2: B for ks 8..15 (covered by the other resident waves)
        #pragma unroll
        for (int ks = 0; ks < 8; ++ks) {
            bw[0][ks] = *(const short8*)(wb + (ks + 8) * 16);
            bw[1][ks] = *(const short8*)(wb + 32 * HH + (ks + 8) * 16);
        }

        // gemm half 2: ks 8..15
        #pragma unroll
        for (int ks = 0; ks < 8; ++ks) {
            #pragma unroll
            for (int mt = 0; mt < 2; ++mt) {
                const short8 afr = *(const short8*)
                    &E[eoff(mt * 32 + l5, 2 * (ks + 8) + half)];
                acc[mt][0] = __builtin_amdgcn_mfma_f32_32x32x16_bf16(
                    afr, bw[0][ks], acc[mt][0], 0, 0, 0);
                acc[mt][1] = __builtin_amdgcn_mfma_f32_32x32x16_bf16(
                    afr, bw[1][ks], acc[mt][1], 0, 0, 0);
            }
        }

        // epilogue: max over 64 anchors (C: col=l5 in nt tile; 2 mt x 16 regs
        // = 32 rows, shfl_down(32) merges lane halves). Valid lanes 0..31.
        #pragma unroll
        for (int nt = 0; nt < 2; ++nt) {
            float m = acc[0][nt][0];
            #pragma unroll
            for (int r = 1; r < 16; ++r) m = fmaxf(m, acc[0][nt][r]);
            #pragma unroll
            for (int r = 0; r < 16; ++r) m = fmaxf(m, acc[1][nt][r]);
            m = fmaxf(m, __shfl_down(m, 32));
            if (type == 0) {
                dmx[nt] = m;  // park d-max in regs until the a-phase
            } else if (lane < 32) {
                out[(base + q) * HH + colw + nt * 32 + l5] =
                    m + dmx[nt] + bias[nt];
            }
        }
    }
}

extern "C" void kernel_launch(void* const* d_in, const int* in_sizes, int n_in,
                              void* d_out, int out_size, void* d_ws, size_t ws_size,
                              hipStream_t stream) {
    const float* points  = (const float*)d_in[0];
    const float* anchors = (const float*)d_in[1];
    // d_in[2] = cor_score: unused by the reference
    const float* Wa = (const float*)d_in[3];
    const float* ba = (const float*)d_in[4];
    const float* Wd = (const float*)d_in[5];
    const float* bd = (const float*)d_in[6];

    unsigned short* wbf = (unsigned short*)d_ws;  // 256 KB: Wd|Wa bf16

    hipLaunchKernelGGL(prep_w_kernel, dim3(256), dim3(256), 0, stream, Wa, Wd, wbf);
    hipLaunchKernelGGL(cgse_main, dim3(NPTS / P_PTS), dim3(256), 0, stream,
                       points, anchors, wbf, ba, bd, (float*)d_out);
}

// Round 12
// 174.730 us; speedup vs baseline: 1.0694x; 1.0694x over previous
//
#include <hip/hip_runtime.h>
#include <hip/hip_bf16.h>
#include <math.h>

// CrossGeometricStructureEmbedding, round 12: barrier-free, LDS-free GEMM.
// R11 post-mortem: (256,3) allocator refuses >64 regs of prefetched B (3rd
// confirmation); (256,2) is the only cap it respects, and there R7's 2
// waves/SIMD stall on barrier+LDS coupling. R12 removes the coupling: the E
// tile is never materialized — each lane computes its MFMA A-fragment's 4
// (sin,cos) pairs directly in registers per (mt,ks). 4x chip-wide sincos
// duplication (trans-pipe ~65k cyc/SIMD = new wall ~37us) buys ZERO LDS
// traffic, ZERO bank conflicts, ZERO main-loop barriers: waves are fully
// independent, so matrix pipe (65k cyc floor) hides under the trans wall
// via m114 co-issue. W held in 128 VGPRs per pass (d-pass then a-pass),
// converted fp32->bf16 inline (prep kernel dropped). d-maxes parked in an
// 8KB LDS array (same-wave write/read, no barrier). (256,2): demand ~176
// arch + 64 AGPR = 240 <= 256, no spill. Grid 512 = 2 blocks/CU resident.

typedef __attribute__((ext_vector_type(8))) short short8;
typedef __attribute__((ext_vector_type(16))) float f32x16;

#define HH 256
#define P_PTS 8
#define NPTS 4096

__device__ __forceinline__ unsigned int pack_bf2(float s, float c) {
    union { __hip_bfloat162 h; unsigned int u; } v;
    v.h = __float22bfloat162_rn(make_float2(s, c));  // low = s, high = c
    return v.u;
}

__global__ __launch_bounds__(256, 2)
void cgse_main(const float* __restrict__ points,
               const float* __restrict__ anchors,
               const float* __restrict__ Wa,
               const float* __restrict__ ba,
               const float* __restrict__ Wd,
               const float* __restrict__ bd,
               float* __restrict__ out) {
    __shared__ float dms[P_PTS][HH];                 // 8 KB d-pass maxes
    __shared__ float xsd[P_PTS][64], xsa[P_PTS][64]; // 4 KB
    __shared__ float anch[192];

    const int tid = threadIdx.x;
    const int wave = tid >> 6, lane = tid & 63;
    const int l5 = lane & 31, half = lane >> 5;
    const int base = blockIdx.x * P_PTS;
    const int colw = wave * 64;                      // wave's 64-col strip

    // ---- anchors + geometry: 8 pts x 64 anchors = 512 tasks / 256 threads
    if (tid < 192) anch[tid] = anchors[tid];
    __syncthreads();
    #pragma unroll
    for (int rep = 0; rep < 2; ++rep) {
        const int task = rep * 256 + tid;
        const int pt = task >> 6, k = task & 63, k2 = (k + 1) & 63;
        const int pn = base + pt;
        const float px = points[pn * 3 + 0], py = points[pn * 3 + 1], pz = points[pn * 3 + 2];
        const float r1x = px - anch[k * 3 + 0];
        const float r1y = py - anch[k * 3 + 1];
        const float r1z = pz - anch[k * 3 + 2];
        const float r2x = px - anch[k2 * 3 + 0];
        const float r2y = py - anch[k2 * 3 + 1];
        const float r2z = pz - anch[k2 * 3 + 2];
        xsd[pt][k] = sqrtf(r1x * r1x + r1y * r1y + r1z * r1z) * 5.0f;  // /SIGMA_D
        const float cx = r1y * r2z - r1z * r2y;
        const float cy = r1z * r2x - r1x * r2z;
        const float cz = r1x * r2y - r1y * r2x;
        const float sv = sqrtf(cx * cx + cy * cy + cz * cz);
        const float cv = r1x * r2x + r1y * r2y + r1z * r2z;
        xsa[pt][k] = atan2f(sv, cv) * 3.8197186342054885f;  // *180/(15*pi)
    }

    float bias[2];
    #pragma unroll
    for (int nt = 0; nt < 2; ++nt)
        bias[nt] = ba[colw + nt * 32 + l5] + bd[colw + nt * 32 + l5];

    // per-lane base frequencies (revolutions): A k-index = ks*16 + half*8 + 2j(+1)
    // pair freq index i = ks*8 + half*4 + j; w_i = rho^i / 2pi, rho = 1e4^(-1/128)
    float BF[4];
    #pragma unroll
    for (int j = 0; j < 4; ++j)
        BF[j] = 0.15915494309189535f
                * __expf(-(float)(half * 4 + j) * 0.0719557841560639f);

    // rho^(8*ks) = 10^(-ks/4)
    const float PK[16] = {
        1.0f, 0.5623413251903491f, 0.31622776601683794f, 0.17782794100389228f,
        0.1f, 0.05623413251903491f, 0.031622776601683794f, 0.017782794100389228f,
        0.01f, 0.005623413251903491f, 0.0031622776601683794f, 0.0017782794100389228f,
        0.001f, 0.0005623413251903491f, 0.00031622776601683794f, 0.00017782794100389228f};

    // ---- W strip (one type per pass): 2 nt x 16 ks x short8 = 128 VGPRs,
    // converted fp32 -> bf16 inline.
    short8 bw[2][16];
    auto loadW = [&](const float* __restrict__ Wp) {
        #pragma unroll
        for (int nt = 0; nt < 2; ++nt) {
            const float* wr = Wp + (colw + nt * 32 + l5) * HH + half * 8;
            #pragma unroll
            for (int ks = 0; ks < 16; ++ks) {
                const float4 f0 = *(const float4*)(wr + ks * 16);
                const float4 f1 = *(const float4*)(wr + ks * 16 + 4);
                union { unsigned int u[4]; short8 s; } v;
                v.u[0] = pack_bf2(f0.x, f0.y);
                v.u[1] = pack_bf2(f0.z, f0.w);
                v.u[2] = pack_bf2(f1.x, f1.y);
                v.u[3] = pack_bf2(f1.z, f1.w);
                bw[nt][ks] = v.s;
            }
        }
    };

    __syncthreads();  // geometry visible; the ONLY barrier before the end

    #pragma unroll 1
    for (int pass = 0; pass < 2; ++pass) {
        loadW(pass ? Wa : Wd);

        #pragma unroll 1
        for (int q = 0; q < P_PTS; ++q) {
            // x for this lane's two A-rows (m = l5 and m = 32+l5)
            const float x0 = (pass ? xsa : xsd)[q][l5];
            const float x1 = (pass ? xsa : xsd)[q][32 + l5];
            float xw[2][4];
            #pragma unroll
            for (int j = 0; j < 4; ++j) {
                xw[0][j] = x0 * BF[j];
                xw[1][j] = x1 * BF[j];
            }

            f32x16 acc[2][2];
            #pragma unroll
            for (int mt = 0; mt < 2; ++mt)
                #pragma unroll
                for (int nt = 0; nt < 2; ++nt)
                    #pragma unroll
                    for (int r = 0; r < 16; ++r) acc[mt][nt][r] = 0.f;

            #pragma unroll
            for (int ks = 0; ks < 16; ++ks) {
                #pragma unroll
                for (int mt = 0; mt < 2; ++mt) {
                    // A-fragment computed straight into registers
                    union { unsigned int u[4]; short8 s; } v;
                    #pragma unroll
                    for (int jj = 0; jj < 4; ++jj) {
                        const float t = xw[mt][jj] * PK[ks];
                        const float f = t - floorf(t);  // revolutions
                        v.u[jj] = pack_bf2(__builtin_amdgcn_sinf(f),
                                           __builtin_amdgcn_cosf(f));
                    }
                    acc[mt][0] = __builtin_amdgcn_mfma_f32_32x32x16_bf16(
                        v.s, bw[0][ks], acc[mt][0], 0, 0, 0);
                    acc[mt][1] = __builtin_amdgcn_mfma_f32_32x32x16_bf16(
                        v.s, bw[1][ks], acc[mt][1], 0, 0, 0);
                }
            }

            // epilogue: max over 64 anchors (C: col=l5 in nt tile; 2 mt x 16
            // regs = 32 rows; shfl_down(32) merges lane halves). lanes 0..31.
            #pragma unroll
            for (int nt = 0; nt < 2; ++nt) {
                float m = acc[0][nt][0];
                #pragma unroll
                for (int r = 1; r < 16; ++r) m = fmaxf(m, acc[0][nt][r]);
                #pragma unroll
                for (int r = 0; r < 16; ++r) m = fmaxf(m, acc[1][nt][r]);
                m = fmaxf(m, __shfl_down(m, 32));
                if (lane < 32) {
                    const int col = colw + nt * 32 + l5;
                    if (pass == 0) dms[q][col] = m;  // same wave reads it later
                    else out[(base + q) * HH + col] = m + dms[q][col] + bias[nt];
                }
            }
        }
    }
}

extern "C" void kernel_launch(void* const* d_in, const int* in_sizes, int n_in,
                              void* d_out, int out_size, void* d_ws, size_t ws_size,
                              hipStream_t stream) {
    const float* points  = (const float*)d_in[0];
    const float* anchors = (const float*)d_in[1];
    // d_in[2] = cor_score: unused by the reference
    const float* Wa = (const float*)d_in[3];
    const float* ba = (const float*)d_in[4];
    const float* Wd = (const float*)d_in[5];
    const float* bd = (const float*)d_in[6];

    hipLaunchKernelGGL(cgse_main, dim3(NPTS / P_PTS), dim3(256), 0, stream,
                       points, anchors, Wa, ba, Wd, bd, (float*)d_out);
}